// Round 1
// baseline (1130.968 us; speedup 1.0000x reference)
//
#include <hip/hip_runtime.h>

// STARLayer: B=4096 rows, D_IN=1024, HIDDEN=[1024,512,256], 8 domains.
// Key insight: output only needs each row's OWN domain path -> 8x less work
// than the reference's all-domain einsum. Strategy:
//   1) bucket rows by domain (one small kernel)
//   2) per-layer grouped GEMM: block = (rowtile within bucket) x (coltile) x domain
//      w_eff = sk * dk[d] fused on LDS load; bias+relu fused in epilogue
//   3) h stored in bucket-permuted order (gather on L0 input, scatter on L2 output)

#define NROWS 4096
#define NDOM 8

__global__ void bucket_kernel(const int* __restrict__ ind,
                              int* __restrict__ offsets,
                              int* __restrict__ rowidx) {
    __shared__ int cnt[NDOM];
    __shared__ int cur[NDOM];
    int t = threadIdx.x;
    if (t < NDOM) cnt[t] = 0;
    __syncthreads();
    for (int b = t; b < NROWS; b += blockDim.x)
        atomicAdd(&cnt[ind[b]], 1);
    __syncthreads();
    if (t == 0) {
        int acc = 0;
        for (int d = 0; d < NDOM; ++d) { offsets[d] = acc; cur[d] = acc; acc += cnt[d]; }
        offsets[NDOM] = acc;
    }
    __syncthreads();
    for (int b = t; b < NROWS; b += blockDim.x) {
        int p = atomicAdd(&cur[ind[b]], 1);
        rowidx[p] = b;
    }
}

// Generic fp32 grouped-GEMM layer.
// A: [*, K] input (GATHER -> index via rowidx, else bucket-ordered rows)
// Out: bucket-ordered [*, N] (SCATTER -> write to rowidx[p] row of d_out)
template <int BM, int BN, int BK, int TM, int TN, bool GATHER, bool SCATTER>
__launch_bounds__((BM / TM) * (BN / TN))
__global__ void star_gemm(const float* __restrict__ A,
                          const float* __restrict__ sk,
                          const float* __restrict__ dk,
                          const float* __restrict__ sb,
                          const float* __restrict__ db,
                          float* __restrict__ Out,
                          const int* __restrict__ offsets,
                          const int* __restrict__ rowidx,
                          int K, int N) {
    constexpr int TX = BN / TN;
    constexpr int TY = BM / TM;
    constexpr int NTHREADS = TX * TY;
    constexpr int A_K4 = BK / 4;                 // float4 chunks per A row
    constexpr int A_ROWS = NTHREADS / A_K4;      // A rows loaded per pass
    constexpr int B_N4 = BN / 4;
    constexpr int B_ROWS = NTHREADS / B_N4;      // B rows loaded per pass
    static_assert(A_ROWS == BM, "A tile must load in one pass");
    static_assert(B_ROWS == BK, "B tile must load in one pass");
    static_assert(TM % 4 == 0 && TN % 4 == 0, "float4 microtile");

    const int d = blockIdx.z;
    const int row_start = offsets[d] + blockIdx.x * BM;
    const int row_end = offsets[d + 1];
    if (row_start >= row_end) return;
    const int n0 = blockIdx.y * BN;

    __shared__ float As[BK][BM + 4];
    __shared__ float Bs[BK][BN + 4];

    const int tid = threadIdx.x;
    const int tx = tid % TX;
    const int ty = tid / TX;

    float acc[TM][TN];
#pragma unroll
    for (int i = 0; i < TM; ++i)
#pragma unroll
        for (int j = 0; j < TN; ++j) acc[i][j] = 0.f;

    // Per-thread load coordinates
    const int a_row = tid / A_K4;
    const int a_k = (tid % A_K4) * 4;
    const int b_k = tid / B_N4;
    const int b_n = (tid % B_N4) * 4;

    const int a_p = row_start + a_row;
    // resolve gathered source row once
    int a_src = 0;
    bool a_valid = (a_p < row_end);
    if (a_valid) a_src = GATHER ? rowidx[a_p] : a_p;
    const float* a_ptr = A + (size_t)a_src * K + a_k;

    const size_t dkbase = (size_t)d * (size_t)K * (size_t)N;
    const float* sk_ptr = sk + (size_t)b_k * N + n0 + b_n;
    const float* dk_ptr = dk + dkbase + (size_t)b_k * N + n0 + b_n;

    for (int k0 = 0; k0 < K; k0 += BK) {
        // ---- A tile (BM x BK), transposed into As[k][m]
        float4 av = make_float4(0.f, 0.f, 0.f, 0.f);
        if (a_valid) av = *(const float4*)(a_ptr + k0);
        As[a_k + 0][a_row] = av.x;
        As[a_k + 1][a_row] = av.y;
        As[a_k + 2][a_row] = av.z;
        As[a_k + 3][a_row] = av.w;

        // ---- B tile (BK x BN): w_eff = sk * dk
        {
            float4 s = *(const float4*)(sk_ptr + (size_t)k0 * N);
            float4 dd = *(const float4*)(dk_ptr + (size_t)k0 * N);
            float4 w = make_float4(s.x * dd.x, s.y * dd.y, s.z * dd.z, s.w * dd.w);
            *(float4*)&Bs[b_k][b_n] = w;
        }
        __syncthreads();

#pragma unroll
        for (int k = 0; k < BK; ++k) {
            float a_reg[TM], b_reg[TN];
#pragma unroll
            for (int i = 0; i < TM; i += 4)
                *(float4*)&a_reg[i] = *(const float4*)&As[k][ty * TM + i];
#pragma unroll
            for (int j = 0; j < TN; j += 4)
                *(float4*)&b_reg[j] = *(const float4*)&Bs[k][tx * TN + j];
#pragma unroll
            for (int i = 0; i < TM; ++i)
#pragma unroll
                for (int j = 0; j < TN; ++j)
                    acc[i][j] += a_reg[i] * b_reg[j];
        }
        __syncthreads();
    }

    // ---- epilogue: bias + relu (+ optional scatter)
#pragma unroll
    for (int i = 0; i < TM; ++i) {
        int p = row_start + ty * TM + i;
        if (p < row_end) {
            int orow = SCATTER ? rowidx[p] : p;
            float* outrow = Out + (size_t)orow * N + n0;
#pragma unroll
            for (int j = 0; j < TN; ++j) {
                int n = tx * TN + j;
                float v = acc[i][j] + sb[n0 + n] + db[(size_t)d * N + n0 + n];
                outrow[n] = v > 0.f ? v : 0.f;
            }
        }
    }
}

extern "C" void kernel_launch(void* const* d_in, const int* in_sizes, int n_in,
                              void* d_out, int out_size, void* d_ws, size_t ws_size,
                              hipStream_t stream) {
    const float* x = (const float*)d_in[0];
    const int* ind = (const int*)d_in[1];
    const float* sk0 = (const float*)d_in[2];
    const float* sb0 = (const float*)d_in[3];
    const float* dk0 = (const float*)d_in[4];
    const float* db0 = (const float*)d_in[5];
    const float* sk1 = (const float*)d_in[6];
    const float* sb1 = (const float*)d_in[7];
    const float* dk1 = (const float*)d_in[8];
    const float* db1 = (const float*)d_in[9];
    const float* sk2 = (const float*)d_in[10];
    const float* sb2 = (const float*)d_in[11];
    const float* dk2 = (const float*)d_in[12];
    const float* db2 = (const float*)d_in[13];
    float* out = (float*)d_out;

    // workspace layout
    char* ws = (char*)d_ws;
    int* offsets = (int*)ws;                       // 9 ints
    int* rowidx = (int*)(ws + 256);                // 4096 ints
    float* h1 = (float*)(ws + 16640);              // 4096*1024 f32 (bucket order)
    float* h2 = h1 + (size_t)NROWS * 1024;         // 4096*512 f32 (bucket order)

    bucket_kernel<<<1, 256, 0, stream>>>(ind, offsets, rowidx);

    // Layer 0: K=1024 -> N=1024 (gather x)
    star_gemm<128, 128, 8, 8, 8, true, false>
        <<<dim3(32, 8, NDOM), 256, 0, stream>>>(x, sk0, dk0, sb0, db0, h1,
                                                offsets, rowidx, 1024, 1024);
    // Layer 1: K=1024 -> N=512
    star_gemm<128, 128, 8, 8, 8, false, false>
        <<<dim3(32, 4, NDOM), 256, 0, stream>>>(h1, sk1, dk1, sb1, db1, h2,
                                                offsets, rowidx, 1024, 512);
    // Layer 2: K=512 -> N=256 (scatter to d_out)
    star_gemm<64, 64, 16, 4, 4, false, true>
        <<<dim3(64, 4, NDOM), 256, 0, stream>>>(h2, sk2, dk2, sb2, db2, out,
                                                offsets, rowidx, 512, 256);
}

// Round 2
// 278.344 us; speedup vs baseline: 4.0632x; 4.0632x over previous
//
#include <hip/hip_runtime.h>
#include <hip/hip_bf16.h>

#define NROWS 4096
#define NDOM 8

typedef short short8 __attribute__((ext_vector_type(8)));
typedef float floatx4 __attribute__((ext_vector_type(4)));

__device__ __forceinline__ unsigned short f2bf(float f) {
    union { float f; unsigned u; } v; v.f = f;
    unsigned r = v.u + 0x7FFFu + ((v.u >> 16) & 1u);  // RNE
    return (unsigned short)(r >> 16);
}

__global__ void bucket_kernel(const int* __restrict__ ind,
                              int* __restrict__ offsets,
                              int* __restrict__ rowidx) {
    __shared__ int cnt[NDOM];
    __shared__ int cur[NDOM];
    int t = threadIdx.x;
    if (t < NDOM) cnt[t] = 0;
    __syncthreads();
    for (int b = t; b < NROWS; b += blockDim.x)
        atomicAdd(&cnt[ind[b]], 1);
    __syncthreads();
    if (t == 0) {
        int acc = 0;
        for (int d = 0; d < NDOM; ++d) { offsets[d] = acc; cur[d] = acc; acc += cnt[d]; }
        offsets[NDOM] = acc;
    }
    __syncthreads();
    for (int b = t; b < NROWS; b += blockDim.x) {
        int p = atomicAdd(&cur[ind[b]], 1);
        rowidx[p] = b;
    }
}

// Grouped GEMM, one 128x128 tile per (domain, m-slot, n-tile).
// A (bf16 or gathered fp32 x) staged as As[m][k] (64 k, chunk-swizzled),
// W staged TRANSPOSED as Ws[n][k] with w_eff = sk*dk fused, bf16.
// MFMA 16x16x32, wave grid 2x2, 4x4 frags per wave.
template <int K, int N, bool GATHER, bool SCATTER>
__launch_bounds__(256)
__global__ void star_gemm(const float* __restrict__ Afp,
                          const unsigned short* __restrict__ Abf,
                          const float* __restrict__ sk,
                          const float* __restrict__ dk,
                          const float* __restrict__ sb,
                          const float* __restrict__ db,
                          float* __restrict__ OutF,
                          unsigned short* __restrict__ OutB,
                          const int* __restrict__ offsets,
                          const int* __restrict__ rowidx) {
    __shared__ unsigned short As[128 * 64];
    __shared__ unsigned short Ws[128 * 64];

    const int gid = blockIdx.x;
    const int d = gid & 7;                  // domain -> XCD (gid % 8 round-robin)
    const int mslot = (gid >> 3) & 7;       // persistent m-slot
    const int n0 = (gid >> 6) * 128;

    const int bstart = offsets[d];
    const int bend = offsets[d + 1];
    const int bsize = bend - bstart;

    const int tid = threadIdx.x;
    const int lane = tid & 63;
    const int wid = tid >> 6;
    const int wy = wid >> 1;
    const int wx = wid & 1;
    const int lm = lane & 15;
    const int quad = lane >> 4;

    float bias[4];
#pragma unroll
    for (int j = 0; j < 4; ++j) {
        int n = n0 + wx * 64 + j * 16 + lm;
        bias[j] = sb[n] + db[d * N + n];
    }

    // W staging coords: thread covers k = wk8*8 + r (r=0..7), n = wn..wn+3
    const int wk8 = tid >> 5;           // 0..7
    const int wn = (tid & 31) * 4;      // 0..124
    // A fp32-gather staging coords: row am, k-half ah
    const int am = tid >> 1;            // 0..127
    const int ah = tid & 1;

    for (int mt = mslot; mt * 128 < bsize; mt += 8) {
        const int row_start = bstart + mt * 128;

        int asrc = 0;
        if constexpr (GATHER) {
            int p = row_start + am; if (p > NROWS - 1) p = NROWS - 1;
            asrc = rowidx[p];
        }

        floatx4 acc[4][4];
#pragma unroll
        for (int i = 0; i < 4; ++i)
#pragma unroll
            for (int j = 0; j < 4; ++j) acc[i][j] = floatx4{0.f, 0.f, 0.f, 0.f};

        for (int k0 = 0; k0 < K; k0 += 64) {
            // ---- stage A (128 rows x 64 k, bf16, chunk-swizzled)
            if constexpr (GATHER) {
#pragma unroll
                for (int r = 0; r < 8; ++r) {
                    int k = ah * 32 + r * 4;
                    float4 v = *(const float4*)(Afp + (size_t)asrc * K + k0 + k);
                    unsigned b01 = (unsigned)f2bf(v.x) | ((unsigned)f2bf(v.y) << 16);
                    unsigned b23 = (unsigned)f2bf(v.z) | ((unsigned)f2bf(v.w) << 16);
                    int phys = (k >> 3) ^ (am & 7);
                    unsigned* dst = (unsigned*)&As[am * 64 + phys * 8 + (k & 7)];
                    dst[0] = b01;
                    dst[1] = b23;
                }
            } else {
#pragma unroll
                for (int r = 0; r < 4; ++r) {
                    int flat = r * 256 + tid;
                    int m = flat >> 3;
                    int ch = flat & 7;
                    int p = row_start + m; if (p > NROWS - 1) p = NROWS - 1;
                    short8 v = *(const short8*)(Abf + (size_t)p * K + k0 + ch * 8);
                    *(short8*)&As[m * 64 + ((ch ^ (m & 7)) * 8)] = v;
                }
            }
            // ---- stage W: w_eff = sk*dk, transposed to [n][k], bf16
            {
                const float* skp = sk + (size_t)(k0 + wk8 * 8) * N + n0 + wn;
                const float* dkp = dk + ((size_t)d * K + k0 + wk8 * 8) * N + n0 + wn;
                unsigned short wb[4][8];
#pragma unroll
                for (int r = 0; r < 8; ++r) {
                    float4 s = *(const float4*)(skp + (size_t)r * N);
                    float4 dd = *(const float4*)(dkp + (size_t)r * N);
                    wb[0][r] = f2bf(s.x * dd.x);
                    wb[1][r] = f2bf(s.y * dd.y);
                    wb[2][r] = f2bf(s.z * dd.z);
                    wb[3][r] = f2bf(s.w * dd.w);
                }
#pragma unroll
                for (int c = 0; c < 4; ++c) {
                    int nn = wn + c;
                    int phys = wk8 ^ (nn & 7);
                    *(short8*)&Ws[nn * 64 + phys * 8] = *(short8*)wb[c];
                }
            }
            __syncthreads();

            // ---- compute: 2 k-steps x 4x4 MFMA 16x16x32
#pragma unroll
            for (int kk = 0; kk < 2; ++kk) {
                short8 av[4], wv[4];
#pragma unroll
                for (int i = 0; i < 4; ++i) {
                    int m = wy * 64 + i * 16 + lm;
                    int phys = (kk * 4 + quad) ^ (m & 7);
                    av[i] = *(const short8*)&As[m * 64 + phys * 8];
                }
#pragma unroll
                for (int j = 0; j < 4; ++j) {
                    int n = wx * 64 + j * 16 + lm;
                    int phys = (kk * 4 + quad) ^ (n & 7);
                    wv[j] = *(const short8*)&Ws[n * 64 + phys * 8];
                }
#pragma unroll
                for (int i = 0; i < 4; ++i)
#pragma unroll
                    for (int j = 0; j < 4; ++j)
                        acc[i][j] = __builtin_amdgcn_mfma_f32_16x16x32_bf16(
                            av[i], wv[j], acc[i][j], 0, 0, 0);
            }
            __syncthreads();
        }

        // ---- epilogue: bias + relu, C layout col=lane&15, row=quad*4+reg
#pragma unroll
        for (int i = 0; i < 4; ++i) {
#pragma unroll
            for (int rg = 0; rg < 4; ++rg) {
                int m = wy * 64 + i * 16 + quad * 4 + rg;
                int p = row_start + m;
                if (p < bend) {
                    if constexpr (SCATTER) {
                        int orow = rowidx[p];
#pragma unroll
                        for (int j = 0; j < 4; ++j) {
                            int n = n0 + wx * 64 + j * 16 + lm;
                            float v = acc[i][j][rg] + bias[j];
                            OutF[(size_t)orow * N + n] = v > 0.f ? v : 0.f;
                        }
                    } else {
#pragma unroll
                        for (int j = 0; j < 4; ++j) {
                            int n = n0 + wx * 64 + j * 16 + lm;
                            float v = acc[i][j][rg] + bias[j];
                            OutB[(size_t)p * N + n] = f2bf(v > 0.f ? v : 0.f);
                        }
                    }
                }
            }
        }
    }
}

extern "C" void kernel_launch(void* const* d_in, const int* in_sizes, int n_in,
                              void* d_out, int out_size, void* d_ws, size_t ws_size,
                              hipStream_t stream) {
    const float* x = (const float*)d_in[0];
    const int* ind = (const int*)d_in[1];
    const float* sk0 = (const float*)d_in[2];
    const float* sb0 = (const float*)d_in[3];
    const float* dk0 = (const float*)d_in[4];
    const float* db0 = (const float*)d_in[5];
    const float* sk1 = (const float*)d_in[6];
    const float* sb1 = (const float*)d_in[7];
    const float* dk1 = (const float*)d_in[8];
    const float* db1 = (const float*)d_in[9];
    const float* sk2 = (const float*)d_in[10];
    const float* sb2 = (const float*)d_in[11];
    const float* dk2 = (const float*)d_in[12];
    const float* db2 = (const float*)d_in[13];
    float* out = (float*)d_out;

    char* ws = (char*)d_ws;
    int* offsets = (int*)ws;                                   // 9 ints
    int* rowidx = (int*)(ws + 256);                            // 4096 ints
    unsigned short* h1b = (unsigned short*)(ws + 32768);       // 4096x1024 bf16 (8MB)
    unsigned short* h2b = h1b + (size_t)NROWS * 1024;          // 4096x512 bf16 (4MB)

    bucket_kernel<<<1, 256, 0, stream>>>(ind, offsets, rowidx);

    // L0: x fp32 gather -> h1b bf16   (K=1024, N=1024): grid 8d*8m*8n
    star_gemm<1024, 1024, true, false><<<512, 256, 0, stream>>>(
        x, nullptr, sk0, dk0, sb0, db0, nullptr, h1b, offsets, rowidx);
    // L1: h1b -> h2b                  (K=1024, N=512): grid 8d*8m*4n
    star_gemm<1024, 512, false, false><<<256, 256, 0, stream>>>(
        nullptr, h1b, sk1, dk1, sb1, db1, nullptr, h2b, offsets, rowidx);
    // L2: h2b -> out fp32 scatter     (K=512, N=256): grid 8d*8m*2n
    star_gemm<512, 256, false, true><<<128, 256, 0, stream>>>(
        nullptr, h2b, sk2, dk2, sb2, db2, out, nullptr, offsets, rowidx);
}